// Round 1
// baseline (511.051 us; speedup 1.0000x reference)
//
#include <hip/hip_runtime.h>
#include <stdint.h>

#define B_ROWS 8192
#define DIM 4096
#define E_CODES 512
#define MARGIN 16.0f

typedef __attribute__((ext_vector_type(8))) short short8;
typedef __attribute__((ext_vector_type(4))) float floatx4;

// ---- workspace layout (float units) ----
#define WS_SCORES 0                       // 8192*512 floats = 4,194,304
#define WS_ENORM  4194304                 // 512 floats
#define WS_COUNTS 4194816                 // 512 ints
#define WS_LOSS   4195328                 // 1 float  (contiguous after counts)

// ---- output layout (float units) ----
#define O_LOSS 0
#define O_Q    1
#define O_PERP 33554433
#define O_ENC  33554434

// ---------------- codebook norms ----------------
__global__ __launch_bounds__(64) void k_enorm(const float* __restrict__ cb, float* __restrict__ enorm) {
    const int e = blockIdx.x;
    const int lane = threadIdx.x;
    const float4* c4 = (const float4*)(cb + (size_t)e * DIM);
    float p = 0.f;
#pragma unroll
    for (int j = 0; j < 16; j++) {
        float4 v = c4[j * 64 + lane];
        p = fmaf(v.x, v.x, fmaf(v.y, v.y, fmaf(v.z, v.z, fmaf(v.w, v.w, p))));
    }
    for (int off = 32; off; off >>= 1) p += __shfl_down(p, off);
    if (lane == 0) enorm[e] = p;
}

// pack two fp32 into (bf16(hi)<<16)|bf16(lo) by truncation — one v_perm_b32
__device__ inline uint32_t pk2(float hi, float lo) {
    return __builtin_amdgcn_perm(__float_as_uint(hi), __float_as_uint(lo), 0x07060302u);
}

// ---------------- approx score GEMM: scores[b][e] = ||e||^2 - 2*(bf16(x).bf16(e)) ----------------
// BM=128, BN=128, BK=32, 4 waves (2x2), each wave 64x64 via 4x4 frags of 16x16x32.
#define LDK 56  // padded LDS row stride in bf16 elems (112B: 16B-aligned, conflict-free frag reads)
__global__ __launch_bounds__(256) void k_gemm(const float* __restrict__ X, const float* __restrict__ CB,
                                              const float* __restrict__ enorm, float* __restrict__ scores) {
    __shared__ __align__(16) unsigned short As[128 * LDK];
    __shared__ __align__(16) unsigned short Bs[128 * LDK];
    const int bn = blockIdx.x & 3;   // code-tile: fixed per XCD (round-robin dispatch) -> codebook slice stays in L2
    const int bm = blockIdx.x >> 2;
    const int tid = threadIdx.x;
    const int lane = tid & 63;
    const int w = tid >> 6, wr = w >> 1, wc = w & 1;
    const int m16 = lane & 15, q4 = lane >> 4;
    const int r = tid >> 1;          // staging row 0..127
    const int ko = (tid & 1) << 4;   // staging k-offset 0/16
    const float* xg = X + (size_t)(bm * 128 + r) * DIM + ko;
    const float* cg = CB + (size_t)(bn * 128 + r) * DIM + ko;

    floatx4 acc[4][4];
#pragma unroll
    for (int i = 0; i < 4; i++)
#pragma unroll
        for (int j = 0; j < 4; j++) acc[i][j] = (floatx4){0.f, 0.f, 0.f, 0.f};

    for (int kt = 0; kt < DIM; kt += 32) {
        const float4* xa = (const float4*)(xg + kt);
        const float4* ca = (const float4*)(cg + kt);
        float4 xv0 = xa[0], xv1 = xa[1], xv2 = xa[2], xv3 = xa[3];
        float4 cv0 = ca[0], cv1 = ca[1], cv2 = ca[2], cv3 = ca[3];
        __syncthreads();  // previous tile's frag reads complete
        *(uint4*)(&As[r * LDK + ko])     = make_uint4(pk2(xv0.y, xv0.x), pk2(xv0.w, xv0.z), pk2(xv1.y, xv1.x), pk2(xv1.w, xv1.z));
        *(uint4*)(&As[r * LDK + ko + 8]) = make_uint4(pk2(xv2.y, xv2.x), pk2(xv2.w, xv2.z), pk2(xv3.y, xv3.x), pk2(xv3.w, xv3.z));
        *(uint4*)(&Bs[r * LDK + ko])     = make_uint4(pk2(cv0.y, cv0.x), pk2(cv0.w, cv0.z), pk2(cv1.y, cv1.x), pk2(cv1.w, cv1.z));
        *(uint4*)(&Bs[r * LDK + ko + 8]) = make_uint4(pk2(cv2.y, cv2.x), pk2(cv2.w, cv2.z), pk2(cv3.y, cv3.x), pk2(cv3.w, cv3.z));
        __syncthreads();
        short8 a[4], b[4];
#pragma unroll
        for (int f = 0; f < 4; f++) {
            a[f] = *(const short8*)(&As[(wr * 64 + f * 16 + m16) * LDK + q4 * 8]);
            b[f] = *(const short8*)(&Bs[(wc * 64 + f * 16 + m16) * LDK + q4 * 8]);
        }
#pragma unroll
        for (int i = 0; i < 4; i++)
#pragma unroll
            for (int j = 0; j < 4; j++)
                acc[i][j] = __builtin_amdgcn_mfma_f32_16x16x32_bf16(a[i], b[j], acc[i][j], 0, 0, 0);
    }

    // epilogue: score = enorm[e] - 2*dot ; C/D layout col=lane&15, row=(lane>>4)*4+reg
#pragma unroll
    for (int fc = 0; fc < 4; fc++) {
        const int col = bn * 128 + wc * 64 + fc * 16 + m16;
        const float en = enorm[col];
#pragma unroll
        for (int fr = 0; fr < 4; fr++) {
            const int row0 = bm * 128 + wr * 64 + fr * 16 + q4 * 4;
#pragma unroll
            for (int rr = 0; rr < 4; rr++)
                scores[(size_t)(row0 + rr) * E_CODES + col] = en - 2.0f * acc[fr][fc][rr];
        }
    }
}

// ---------------- fused: argmin (w/ exact fp32 refinement), quantize, encodings, loss ----------------
__global__ __launch_bounds__(256) void k_fused(const float* __restrict__ X, const float* __restrict__ CB,
                                               const float* __restrict__ scores, int* __restrict__ counts,
                                               float* __restrict__ loss_sum, float* __restrict__ out) {
    const int row = blockIdx.x;
    const int tid = threadIdx.x;
    const int lane = tid & 63, w = tid >> 6;
    __shared__ float redv[4];
    __shared__ int redi[4];
    __shared__ int cand[64];
    __shared__ int ncand;

    float s0 = scores[(size_t)row * E_CODES + tid];
    float s1 = scores[(size_t)row * E_CODES + 256 + tid];
    if (tid == 0) ncand = 0;

    // block-wide approx min (tie -> lower index)
    float mv; int mi;
    if (s1 < s0) { mv = s1; mi = tid + 256; } else { mv = s0; mi = tid; }
    for (int off = 32; off; off >>= 1) {
        float ov = __shfl_down(mv, off);
        int   oi = __shfl_down(mi, off);
        if (ov < mv || (ov == mv && oi < mi)) { mv = ov; mi = oi; }
    }
    if (lane == 0) { redv[w] = mv; redi[w] = mi; }
    __syncthreads();
    if (tid == 0) {
        for (int k = 1; k < 4; k++)
            if (redv[k] < redv[0] || (redv[k] == redv[0] && redi[k] < redi[0])) { redv[0] = redv[k]; redi[0] = redi[k]; }
    }
    __syncthreads();
    const float thr = redv[0] + MARGIN;

    // gather candidates within margin (bf16 approx error << MARGIN)
    if (s0 <= thr) { int p = atomicAdd(&ncand, 1); if (p < 64) cand[p] = tid; }
    if (s1 <= thr) { int p = atomicAdd(&ncand, 1); if (p < 64) cand[p] = tid + 256; }
    __syncthreads();
    const int nc = min(ncand, 64);

    // exact fp32 evaluation of candidates; lexicographic (dist, index) min
    const float* xr = X + (size_t)row * DIM;
    float bestd = 3.0e38f; int beste = 1 << 30;
    for (int c = 0; c < nc; c++) {
        const int e = cand[c];
        const float* cr = CB + (size_t)e * DIM;
        float p = 0.f;
#pragma unroll
        for (int j = 0; j < 16; j++) {
            const int idx = j * 256 + tid;
            const float d = xr[idx] - cr[idx];
            p = fmaf(d, d, p);
        }
        for (int off = 32; off; off >>= 1) p += __shfl_down(p, off);
        __syncthreads();                 // protect redv reuse
        if (lane == 0) redv[w] = p;
        __syncthreads();
        const float dist = ((redv[0] + redv[1]) + redv[2]) + redv[3];  // identical on all threads
        if (dist < bestd || (dist == bestd && e < beste)) { bestd = dist; beste = e; }
    }

    // outputs: quantized_st (straight-through forward = x + (q - x)), one-hot row, count, loss partial
    const float* cq = CB + (size_t)beste * DIM;
    float* oq = out + O_Q + (size_t)row * DIM;
#pragma unroll
    for (int j = 0; j < 16; j++) {
        const int idx = j * 256 + tid;
        const float x = xr[idx];
        const float q = cq[idx];
        oq[idx] = x + (q - x);
    }
    float* oe = out + O_ENC + (size_t)row * E_CODES;
    oe[tid]       = (tid == beste) ? 1.0f : 0.0f;
    oe[tid + 256] = (tid + 256 == beste) ? 1.0f : 0.0f;
    if (tid == 0) {
        atomicAdd(&counts[beste], 1);
        atomicAdd(loss_sum, bestd);      // bestd == sum((q-x)^2) for this row, exact
    }
}

// ---------------- loss + perplexity ----------------
__global__ __launch_bounds__(512) void k_final(const int* __restrict__ counts, const float* __restrict__ loss_sum,
                                               float* __restrict__ out) {
    const int tid = threadIdx.x;
    const int lane = tid & 63, w = tid >> 6;
    __shared__ float r[8];
    const float p = (float)counts[tid] * (1.0f / 8192.0f);
    float h = p * logf(p + 1e-10f);
    for (int off = 32; off; off >>= 1) h += __shfl_down(h, off);
    if (lane == 0) r[w] = h;
    __syncthreads();
    if (tid == 0) {
        float H = 0.f;
        for (int k = 0; k < 8; k++) H += r[k];
        out[O_PERP] = expf(-H);
        out[O_LOSS] = loss_sum[0] * (1.25f / 33554432.0f);  // (q_latent + 0.25*e_latent) = 1.25 * MSE
    }
}

extern "C" void kernel_launch(void* const* d_in, const int* in_sizes, int n_in,
                              void* d_out, int out_size, void* d_ws, size_t ws_size,
                              hipStream_t stream) {
    const float* X  = (const float*)d_in[0];   // inputs  [8192, 8,8,8,8] -> [8192,4096]
    const float* CB = (const float*)d_in[1];   // codebook [512, 4096]
    float* out = (float*)d_out;
    float* ws  = (float*)d_ws;
    float* scores = ws + WS_SCORES;
    float* enorm  = ws + WS_ENORM;
    int*   counts = (int*)(ws + WS_COUNTS);
    float* loss_s = ws + WS_LOSS;

    // counts[512] + loss_sum are contiguous: zero both in one memset (ws is re-poisoned each call)
    hipMemsetAsync(counts, 0, (E_CODES + 1) * sizeof(int), stream);

    k_enorm<<<E_CODES, 64, 0, stream>>>(CB, enorm);
    k_gemm<<<256, 256, 0, stream>>>(X, CB, enorm, scores);
    k_fused<<<B_ROWS, 256, 0, stream>>>(X, CB, scores, counts, loss_s, out);
    k_final<<<1, 512, 0, stream>>>(counts, loss_s, out);
}

// Round 2
// 468.084 us; speedup vs baseline: 1.0918x; 1.0918x over previous
//
#include <hip/hip_runtime.h>
#include <stdint.h>

#define B_ROWS 8192
#define DIM 4096
#define E_CODES 512
#define MARGIN 16.0f

typedef __attribute__((ext_vector_type(8))) short short8;
typedef __attribute__((ext_vector_type(4))) float floatx4;
typedef __attribute__((ext_vector_type(4), aligned(4))) float f4u;  // unaligned-ok float4

// ---- workspace layout (float units) ----
#define WS_SCORES 0                       // 8192*512 floats
#define WS_ENORM  4194304                 // 512 floats
#define WS_COUNTS 4194816                 // 512 ints
#define WS_LOSS   4195328                 // 1 float (contiguous after counts)

// ---- output layout (float units) ----
#define O_LOSS 0
#define O_Q    1
#define O_PERP 33554433
#define O_ENC  33554434

// ---------------- codebook norms ----------------
__global__ __launch_bounds__(64) void k_enorm(const float* __restrict__ cb, float* __restrict__ enorm) {
    const int e = blockIdx.x;
    const int lane = threadIdx.x;
    const float4* c4 = (const float4*)(cb + (size_t)e * DIM);
    float p = 0.f;
#pragma unroll
    for (int j = 0; j < 16; j++) {
        float4 v = c4[j * 64 + lane];
        p = fmaf(v.x, v.x, fmaf(v.y, v.y, fmaf(v.z, v.z, fmaf(v.w, v.w, p))));
    }
    for (int off = 32; off; off >>= 1) p += __shfl_down(p, off);
    if (lane == 0) enorm[e] = p;
}

// pack two fp32 into (bf16(hi)<<16)|bf16(lo) by truncation — one v_perm_b32
__device__ inline uint32_t pk2(float hi, float lo) {
    return __builtin_amdgcn_perm(__float_as_uint(hi), __float_as_uint(lo), 0x07060302u);
}

// ---------------- approx score GEMM: scores[b][e] = ||e||^2 - 2*(bf16(x).bf16(e)) ----------------
// BM=64, BN=128, BK=64. 512 threads = 8 waves (2 m x 4 n), wave = 32x32 via 2x2 frags of 16x16x32.
// grid = 128*4 = 512 blocks -> 2 blocks/CU, 16 waves/CU resident.
#define LDK 72  // padded LDS row stride (bf16 elems); 144 B
__global__ __launch_bounds__(512) void k_gemm(const float* __restrict__ X, const float* __restrict__ CB,
                                              const float* __restrict__ enorm, float* __restrict__ scores) {
    __shared__ __align__(16) unsigned short As[64 * LDK];
    __shared__ __align__(16) unsigned short Bs[128 * LDK];
    const int bm = blockIdx.x >> 2;
    const int bn = blockIdx.x & 3;
    const int tid = threadIdx.x;
    const int lane = tid & 63;
    const int w = tid >> 6, wr = w >> 2, wc = w & 3;
    const int m16 = lane & 15, q4 = lane >> 4;

    // staging assignments
    const int rA = tid >> 3, cA = (tid & 7) * 8;    // A: 64 rows x 64 floats, 8 floats/thread
    const int rB = tid >> 2, cB = (tid & 3) * 16;   // B: 128 rows x 64 floats, 16 floats/thread
    const float* xg = X + (size_t)(bm * 64 + rA) * DIM + cA;
    const float* cg = CB + (size_t)(bn * 128 + rB) * DIM + cB;

    floatx4 acc[2][2];
#pragma unroll
    for (int i = 0; i < 2; i++)
#pragma unroll
        for (int j = 0; j < 2; j++) acc[i][j] = (floatx4){0.f, 0.f, 0.f, 0.f};

    for (int kt = 0; kt < DIM; kt += 64) {
        const float4* xa = (const float4*)(xg + kt);
        const float4* ca = (const float4*)(cg + kt);
        float4 xv0 = xa[0], xv1 = xa[1];
        float4 cv0 = ca[0], cv1 = ca[1], cv2 = ca[2], cv3 = ca[3];
        __syncthreads();  // previous tile's frag reads complete
        *(uint4*)(&As[rA * LDK + cA]) = make_uint4(pk2(xv0.y, xv0.x), pk2(xv0.w, xv0.z), pk2(xv1.y, xv1.x), pk2(xv1.w, xv1.z));
        *(uint4*)(&Bs[rB * LDK + cB])     = make_uint4(pk2(cv0.y, cv0.x), pk2(cv0.w, cv0.z), pk2(cv1.y, cv1.x), pk2(cv1.w, cv1.z));
        *(uint4*)(&Bs[rB * LDK + cB + 8]) = make_uint4(pk2(cv2.y, cv2.x), pk2(cv2.w, cv2.z), pk2(cv3.y, cv3.x), pk2(cv3.w, cv3.z));
        __syncthreads();
        short8 a[2][2], b[2][2];
#pragma unroll
        for (int i = 0; i < 2; i++)
#pragma unroll
            for (int kk = 0; kk < 2; kk++) {
                a[i][kk] = *(const short8*)(&As[(wr * 32 + i * 16 + m16) * LDK + kk * 32 + q4 * 8]);
                b[i][kk] = *(const short8*)(&Bs[(wc * 32 + i * 16 + m16) * LDK + kk * 32 + q4 * 8]);
            }
#pragma unroll
        for (int kk = 0; kk < 2; kk++)
#pragma unroll
            for (int i = 0; i < 2; i++)
#pragma unroll
                for (int j = 0; j < 2; j++)
                    acc[i][j] = __builtin_amdgcn_mfma_f32_16x16x32_bf16(a[i][kk], b[j][kk], acc[i][j], 0, 0, 0);
    }

    // epilogue: score = enorm[e] - 2*dot ; C/D layout col=lane&15, row=(lane>>4)*4+reg
#pragma unroll
    for (int j = 0; j < 2; j++) {
        const int col = bn * 128 + wc * 32 + j * 16 + m16;
        const float en = enorm[col];
#pragma unroll
        for (int i = 0; i < 2; i++) {
            const int row0 = bm * 64 + wr * 32 + i * 16 + q4 * 4;
#pragma unroll
            for (int rr = 0; rr < 4; rr++)
                scores[(size_t)(row0 + rr) * E_CODES + col] = en - 2.0f * acc[i][j][rr];
        }
    }
}

// ---------------- fused: wave-per-row argmin + exact refine + quantize + one-hot + loss ----------------
// grid = 2048 blocks x 256 threads; 4 waves/block, one row per wave; no LDS, no __syncthreads.
__global__ __launch_bounds__(256) void k_fused(const float* __restrict__ X, const float* __restrict__ CB,
                                               const float* __restrict__ scores, int* __restrict__ counts,
                                               float* __restrict__ loss_sum, float* __restrict__ out) {
    const int tid = threadIdx.x;
    const int lane = tid & 63, w = tid >> 6;
    const int row = blockIdx.x * 4 + w;

    const float* sr = scores + (size_t)row * E_CODES;
    float s[8];
#pragma unroll
    for (int g = 0; g < 8; g++) s[g] = sr[g * 64 + lane];

    // wave argmin (approx scores), tie -> lower index
    float mv = s[0]; int mi = lane;
#pragma unroll
    for (int g = 1; g < 8; g++) { if (s[g] < mv) { mv = s[g]; mi = g * 64 + lane; } }
    for (int off = 32; off; off >>= 1) {
        float ov = __shfl_xor(mv, off); int oi = __shfl_xor(mi, off);
        if (ov < mv || (ov == mv && oi < mi)) { mv = ov; mi = oi; }
    }
    const float thr = mv + MARGIN;

    // X row resident in registers
    const float4* xr4 = (const float4*)(X + (size_t)row * DIM);
    float4 xv[16];
#pragma unroll
    for (int i = 0; i < 16; i++) xv[i] = xr4[i * 64 + lane];

    // exact fp32 evaluation of margin candidates; butterfly sums are bit-identical on all lanes
    float bestd = 3.0e38f; int beste = 1 << 30;
#pragma unroll 1
    for (int g = 0; g < 8; g++) {
        unsigned long long mask = __ballot(s[g] <= thr);
        while (mask) {
            const int b = __builtin_ctzll(mask); mask &= mask - 1;
            const int e = g * 64 + b;
            const float4* cr4 = (const float4*)(CB + (size_t)e * DIM);
            float p = 0.f;
#pragma unroll
            for (int i = 0; i < 16; i++) {
                float4 c = cr4[i * 64 + lane];
                float dx = xv[i].x - c.x, dy = xv[i].y - c.y, dz = xv[i].z - c.z, dw = xv[i].w - c.w;
                p = fmaf(dx, dx, fmaf(dy, dy, fmaf(dz, dz, fmaf(dw, dw, p))));
            }
            for (int off = 32; off; off >>= 1) p += __shfl_xor(p, off);
            if (p < bestd || (p == bestd && e < beste)) { bestd = p; beste = e; }
        }
    }

    // quantized_st = x + (q - x), fp32 semantics of the reference
    const float4* cq4 = (const float4*)(CB + (size_t)beste * DIM);
    f4u* oq4 = (f4u*)(out + O_Q + (size_t)row * DIM);   // out+1 is only 4B-aligned
#pragma unroll
    for (int i = 0; i < 16; i++) {
        float4 x = xv[i], q = cq4[i * 64 + lane];
        f4u r;
        r.x = x.x + (q.x - x.x); r.y = x.y + (q.y - x.y);
        r.z = x.z + (q.z - x.z); r.w = x.w + (q.w - x.w);
        oq4[i * 64 + lane] = r;
    }

    // one-hot row (O_ENC is 8B-aligned -> float2)
    float2* oe2 = (float2*)(out + O_ENC + (size_t)row * E_CODES);
#pragma unroll
    for (int k = 0; k < 4; k++) {
        const int e0 = (k * 64 + lane) * 2;
        float2 v; v.x = (e0 == beste) ? 1.0f : 0.0f; v.y = (e0 + 1 == beste) ? 1.0f : 0.0f;
        oe2[k * 64 + lane] = v;
    }

    if (lane == 0) {
        atomicAdd(&counts[beste], 1);
        atomicAdd(loss_sum, bestd);      // bestd == sum((q-x)^2), exact fp32
    }
}

// ---------------- loss + perplexity ----------------
__global__ __launch_bounds__(512) void k_final(const int* __restrict__ counts, const float* __restrict__ loss_sum,
                                               float* __restrict__ out) {
    const int tid = threadIdx.x;
    const int lane = tid & 63, w = tid >> 6;
    __shared__ float r[8];
    const float p = (float)counts[tid] * (1.0f / 8192.0f);
    float h = p * logf(p + 1e-10f);
    for (int off = 32; off; off >>= 1) h += __shfl_down(h, off);
    if (lane == 0) r[w] = h;
    __syncthreads();
    if (tid == 0) {
        float H = 0.f;
        for (int k = 0; k < 8; k++) H += r[k];
        out[O_PERP] = expf(-H);
        out[O_LOSS] = loss_sum[0] * (1.25f / 33554432.0f);  // q_latent + 0.25*e_latent = 1.25*MSE
    }
}

extern "C" void kernel_launch(void* const* d_in, const int* in_sizes, int n_in,
                              void* d_out, int out_size, void* d_ws, size_t ws_size,
                              hipStream_t stream) {
    const float* X  = (const float*)d_in[0];   // inputs  [8192, 8,8,8,8] -> [8192,4096]
    const float* CB = (const float*)d_in[1];   // codebook [512, 4096]
    float* out = (float*)d_out;
    float* ws  = (float*)d_ws;
    float* scores = ws + WS_SCORES;
    float* enorm  = ws + WS_ENORM;
    int*   counts = (int*)(ws + WS_COUNTS);
    float* loss_s = ws + WS_LOSS;

    hipMemsetAsync(counts, 0, (E_CODES + 1) * sizeof(int), stream);

    k_enorm<<<E_CODES, 64, 0, stream>>>(CB, enorm);
    k_gemm<<<512, 512, 0, stream>>>(X, CB, enorm, scores);
    k_fused<<<B_ROWS / 4, 256, 0, stream>>>(X, CB, scores, counts, loss_s, out);
    k_final<<<1, 512, 0, stream>>>(counts, loss_s, out);
}